// Round 2
// baseline (292.300 us; speedup 1.0000x reference)
//
#include <hip/hip_runtime.h>

#define IN_SIZE 256
#define OUT_SIZE 64
#define N_NODES 512
#define FAN_IN 32
#define T_DIM 2048
#define D_DIM 832
#define TOTAL_EDGE 16384
#define BLK_F4 1088   // per-node: 1024 f4 butterfly pairs + 64 f4 entries
#define MAX_ENT 64
#define THRESH -20.0f

// DPP wave64 sum (lane 63 ends with total) — validated rounds 3..9
template <int CTRL, int RM>
__device__ __forceinline__ float dppadd(float v) {
  int m = __builtin_amdgcn_update_dpp(0, __float_as_int(v), CTRL, RM, 0xf, true);
  return v + __int_as_float(m);
}
__device__ __forceinline__ void wave_sum2(float& a, float& b) {
  a = dppadd<0x111, 0xf>(a); b = dppadd<0x111, 0xf>(b);
  a = dppadd<0x112, 0xf>(a); b = dppadd<0x112, 0xf>(b);
  a = dppadd<0x114, 0xf>(a); b = dppadd<0x114, 0xf>(b);
  a = dppadd<0x118, 0xf>(a); b = dppadd<0x118, 0xf>(b);
  a = dppadd<0x142, 0xa>(a); b = dppadd<0x142, 0xa>(b);
  a = dppadd<0x143, 0xc>(a); b = dppadd<0x143, 0xc>(b);
}
__device__ __forceinline__ float rl63(float v) {
  return __int_as_float(__builtin_amdgcn_readlane(__float_as_int(v), 63));
}

// L2-warming touch: global line -> trash LDS, no VGPR dest; drained once at
// kernel epilogue (never read).
__device__ __forceinline__ void warm16(const void* g, void* l) {
  __builtin_amdgcn_global_load_lds(
      (__attribute__((address_space(1))) void*)(uintptr_t)g,
      (__attribute__((address_space(3))) void*)(uintptr_t)l, 16, 0, 0);
}

// ---------------------------------------------------------------------------
// Prep: repack (w1,w2) -> coalesced float2 for kv_kernel. Pure map, no
// atomics, no host-side memset required.
// ---------------------------------------------------------------------------
__global__ __launch_bounds__(256) void prep_kernel(
    const float* __restrict__ weights, float2* __restrict__ w12) {
  int e = blockIdx.x * 256 + threadIdx.x;
  if (e >= TOTAL_EDGE) return;
  const float* wp = weights + (size_t)e * 3;
  w12[e] = make_float2(wp[1], wp[2]);
}

// ---------------------------------------------------------------------------
// KV build (t-major, rows staged in LDS). Split: 2 blocks per 8-row group,
// 4 node-tiles each (2 blocks/CU). Rows staged as float4; weights from the
// coalesced w12 repack. Writes (k,v) t-order into blk KV area; slot 2047=0.
// ---------------------------------------------------------------------------
__global__ __launch_bounds__(256) void kv_kernel(
    const float* __restrict__ actives, const int* __restrict__ in_idxs,
    const float2* __restrict__ w12, float2* __restrict__ KVd) {
  __shared__ float rows[8][836];  // 836 floats/row: float4-aligned row base
  __shared__ int s_idx[64 * FAN_IN];
  __shared__ float2 s_w[64 * FAN_IN];
  int tid = threadIdx.x;
  int tb = (blockIdx.x >> 1) * 8;
  int t0 = (blockIdx.x & 1) * 4;
#pragma unroll
  for (int r = 0; r < 8; ++r) {
    int t = tb + r;
    for (int c = tid; c < 208; c += 256) {  // 208 float4 = 832 floats
      float4 v4 = make_float4(0.f, 0.f, 0.f, 0.f);
      if (t < T_DIM - 1)
        v4 = ((const float4*)(actives + (size_t)(t + 1) * D_DIM))[c];
      *(float4*)&rows[r][4 * c] = v4;
    }
  }
  int tl = tid & 7, ng = tid >> 3;
  for (int tile = t0; tile < t0 + 4; ++tile) {
    __syncthreads();
    int n0 = tile * 64;
    for (int i = tid; i < 64 * FAN_IN; i += 256) {
      int g = n0 * FAN_IN + i;
      s_idx[i] = in_idxs[g];
      s_w[i] = w12[g];
    }
    __syncthreads();
#pragma unroll
    for (int it = 0; it < 2; ++it) {
      int nl = ng + 32 * it;
      const int* ip = &s_idx[nl * FAN_IN];
      const float2* wp = &s_w[nl * FAN_IN];
      float k = 0.f, v = 0.f;
#pragma unroll 8
      for (int f = 0; f < FAN_IN; ++f) {
        float a = rows[tl][ip[f]];
        float2 w = wp[f];
        k = fmaf(w.x, a, k);
        v = fmaf(w.y, a, v);
      }
      KVd[(size_t)(n0 + nl) * (2 * BLK_F4) + tb + tl] = make_float2(k, v);
    }
  }
}

// ---------------------------------------------------------------------------
// Block build: bucket-sort k ascending -> butterfly pairs
// B[p]=(asc_k,asc_v,desc_k,desc_v) p<1024; entries at B[1024..1087]
// (consumers c > node ONLY — dead edges c<=node excluded: with level-parallel
// execution their scatter would race a same-level read; reference reads 0).
// meta (kmax/kmin/cnt + skip bounds at 64-pair chunk0) -> meta_g; base -> Qb.
// ---------------------------------------------------------------------------
__global__ __launch_bounds__(256) void block_kernel(
    const float* __restrict__ x, const int* __restrict__ in_idxs,
    const float* __restrict__ weights, float4* __restrict__ blk,
    float4* __restrict__ meta_g, float4* __restrict__ Qb) {
  __shared__ float2 skv[T_DIM], sbk[T_DIM];
  __shared__ int hist[64];
  __shared__ float smx[4], smn[4];
  __shared__ float4 sEnt[MAX_ENT];
  __shared__ int ecnt;
  int node = blockIdx.x, tid = threadIdx.x;
  if (tid == 0) ecnt = 0;
  const float2* src = (const float2*)(blk + (size_t)node * BLK_F4);
  float mx = -3.4e38f, mn = 3.4e38f;
#pragma unroll
  for (int j = 0; j < 8; ++j) {
    int t = j * 256 + tid;
    float2 kv = (t < 2047) ? src[t] : make_float2(0.f, 0.f);
    skv[t] = kv;
    if (t < 2047) { mx = fmaxf(mx, kv.x); mn = fminf(mn, kv.x); }
  }
  if (tid < 64) hist[tid] = 0;
#pragma unroll
  for (int off = 32; off > 0; off >>= 1) {
    mx = fmaxf(mx, __shfl_xor(mx, off));
    mn = fminf(mn, __shfl_xor(mn, off));
  }
  if ((tid & 63) == 0) { smx[tid >> 6] = mx; smn[tid >> 6] = mn; }
  __syncthreads();
  float kmax = fmaxf(fmaxf(smx[0], smx[1]), fmaxf(smx[2], smx[3]));
  float kmin = fminf(fminf(smn[0], smn[1]), fminf(smn[2], smn[3]));
  float invbw = 64.0f / (kmax - kmin);
#pragma unroll
  for (int j = 0; j < 8; ++j) {
    int t = j * 256 + tid;
    if (t < 2047) {
      int b = (int)((skv[t].x - kmin) * invbw);
      b = b < 0 ? 0 : (b > 63 ? 63 : b);
      atomicAdd(&hist[b], 1);
    }
  }
  // consumer entries: edges e with in_idxs[e]==256+node and consumer > node
  {
    int target = IN_SIZE + node;
    for (int e = tid; e < TOTAL_EDGE; e += 256) {
      if (in_idxs[e] == target) {
        int c = e >> 5;
        if (c > node) {
          int p = atomicAdd(&ecnt, 1);
          if (p < MAX_ENT) {
            const float* wp = weights + (size_t)e * 3;
            sEnt[p] = make_float4(__int_as_float(c), wp[0], wp[1], wp[2]);
          }
        }
      }
    }
  }
  __syncthreads();
  if (tid < 64) {
    int v = hist[tid];
    int incl = v;
#pragma unroll
    for (int d = 1; d < 64; d <<= 1) {
      int u = __shfl_up(incl, d);
      if (tid >= d) incl += u;
    }
    hist[tid] = incl - v;
  }
  if (tid == 0) sbk[2047] = make_float2(0.f, 0.f);
  __syncthreads();
#pragma unroll
  for (int j = 0; j < 8; ++j) {
    int t = j * 256 + tid;
    if (t < 2047) {
      int b = (int)((skv[t].x - kmin) * invbw);
      b = b < 0 ? 0 : (b > 63 ? 63 : b);
      int p = atomicAdd(&hist[b], 1);
      sbk[p] = skv[t];
    }
  }
  // base dot from x (node inputs >= IN_SIZE contribute via scatters)
  if (tid < 32) {
    int g = node * FAN_IN + tid;
    int idx = in_idxs[g];
    const float* wp = weights + (size_t)g * 3;
    float a = (idx < IN_SIZE) ? x[idx] : 0.f;
    float p0 = a * wp[0], p1 = a * wp[1], p2 = a * wp[2];
#pragma unroll
    for (int off = 16; off > 0; off >>= 1) {
      p0 += __shfl_xor(p0, off);
      p1 += __shfl_xor(p1, off);
      p2 += __shfl_xor(p2, off);
    }
    if (tid == 0) Qb[node] = make_float4(p0, p1, p2, 0.f);
  }
  __syncthreads();
  float4* B = blk + (size_t)node * BLK_F4;
  for (int i = tid; i < 1024; i += 256) {
    float2 a = sbk[i];
    float2 d = sbk[2046 - i];
    B[i] = make_float4(a.x, a.y, d.x, d.y);
  }
  int cnt = ecnt < MAX_ENT ? ecnt : MAX_ENT;
  if (tid < MAX_ENT)
    B[1024 + tid] = (tid < cnt) ? sEnt[tid] : make_float4(0.f, 0.f, 0.f, 0.f);
  if (tid == 0)
    meta_g[3 * node + 0] =
        make_float4(kmax, kmin, __int_as_float(cnt), sbk[64].x);
  if (tid == 1)
    meta_g[3 * node + 1] =
        make_float4(sbk[1982].x, sbk[256].x, sbk[1790].x, sbk[512].x);
  if (tid == 2)
    meta_g[3 * node + 2] = make_float4(sbk[1534].x, 0.f, 0.f, 0.f);
}

// ---------------------------------------------------------------------------
// Level sweep: 1 block x 1024 thr (16 waves). Prologue: DAG levels + counting
// sort. Main loop:
//  * next-level prefetch issued at the TOP of each phase (2 register sets,
//    dist-1-at-top) so flight time is covered by the whole current level;
//  * raw s_barrier with lgkmcnt(0)-only drain (LDS scatters are the only
//    cross-wave communication) — global prefetches stay in flight across the
//    barrier instead of the implicit vmcnt(0) drain of __syncthreads;
//  * each prefetch also L2-warms the node's tail region (120 cache lines,
//    2 line-stride global_load_lds into trash LDS; drained once at epilogue)
//    so on-demand p1/p2/p3 tail loads hit XCD-L2 instead of L3/HBM.
// ---------------------------------------------------------------------------
__global__ __launch_bounds__(1024) void sweep_kernel(
    const int* __restrict__ in_idxs, const float4* __restrict__ Qb,
    const float4* __restrict__ meta_g, const float4* __restrict__ blk,
    float* __restrict__ out) {
  __shared__ float4 sQKV[N_NODES];
  __shared__ float4 sMeta[N_NODES][3];
  __shared__ int sLevel[N_NODES];
  __shared__ int sOrder[N_NODES];
  __shared__ int sStart[N_NODES + 1];
  __shared__ int sCur[N_NODES + 1];
  __shared__ int wtot[8];
  __shared__ int sFlag, sNlev;
  __shared__ float souts[OUT_SIZE];
  __shared__ float4 sTrash[64];  // warm-load sink (contents never read)
  const int tid = threadIdx.x;
  const int lane = tid & 63;
  const int w = tid >> 6;

  for (int n = tid; n < N_NODES; n += 1024) {
    sQKV[n] = Qb[n];
    sMeta[n][0] = meta_g[3 * n + 0];
    sMeta[n][1] = meta_g[3 * n + 1];
    sMeta[n][2] = meta_g[3 * n + 2];
    sLevel[n] = 0;
  }
  if (tid == 0) { sFlag = 1; sNlev = 0; }
  // per-thread pred list in regs (tid < 512)
  int pidx[32];
  if (tid < N_NODES) {
    const int4* ip = (const int4*)(in_idxs + tid * FAN_IN);
#pragma unroll
    for (int j = 0; j < 8; ++j) {
      int4 v = ip[j];
      pidx[4 * j + 0] = v.x; pidx[4 * j + 1] = v.y;
      pidx[4 * j + 2] = v.z; pidx[4 * j + 3] = v.w;
    }
  }
  __syncthreads();

  // ---- level relaxation (monotone Bellman-Ford in LDS) ----
  bool again = true;
  while (again) {
    if (tid == 0) sFlag = 0;
    __syncthreads();
    bool ch = false;
    if (tid < N_NODES) {
      int nl = 0;
#pragma unroll
      for (int f = 0; f < FAN_IN; ++f) {
        int p = pidx[f] - IN_SIZE;
        if (p >= 0 && p < tid) {
          int lp = sLevel[p] + 1;
          nl = nl > lp ? nl : lp;
        }
      }
      if (nl > sLevel[tid]) { sLevel[tid] = nl; ch = true; }
    }
    if (ch) sFlag = 1;
    __syncthreads();
    again = (sFlag != 0);
  }

  // ---- counting sort by level ----
  for (int i = tid; i <= N_NODES; i += 1024) sCur[i] = 0;
  __syncthreads();
  if (tid < N_NODES) {
    atomicAdd(&sCur[sLevel[tid]], 1);
    atomicMax(&sNlev, sLevel[tid] + 1);
  }
  __syncthreads();
  int incl = 0;
  if (tid < N_NODES) {
    incl = sCur[tid];
#pragma unroll
    for (int d = 1; d < 64; d <<= 1) {
      int u = __shfl_up(incl, d);
      if ((tid & 63) >= d) incl += u;
    }
    if ((tid & 63) == 63) wtot[tid >> 6] = incl;
  }
  __syncthreads();
  if (tid < N_NODES) {
    int add = 0;
    for (int ww = 0; ww < (tid >> 6); ++ww) add += wtot[ww];
    sStart[tid + 1] = incl + add;
    if (tid == 0) sStart[0] = 0;
  }
  __syncthreads();
  for (int i = tid; i < N_NODES; i += 1024) sCur[i] = sStart[i];
  __syncthreads();
  if (tid < N_NODES) {
    int p = atomicAdd(&sCur[sLevel[tid]], 1);
    sOrder[p] = tid;
  }
  __syncthreads();

  const int nlev = sNlev;

  auto process = [&](int node, float4 C0, float4 ENT) {
    float4 qv = sQKV[node];
    float4 m0 = sMeta[node][0];
    float4 m1 = sMeta[node][1];
    float4 m2 = sMeta[node][2];
    float q = qv.x, kl = qv.y, vl = qv.z;
    int cnt = __float_as_int(m0.z);
    float m = fmaxf(fmaxf(q * m0.x, q * m0.y), q * kl);
    bool p1 = fmaxf(q * m0.w, q * m1.x) - m >= THRESH;          // pairs 64..255
    bool p2 = p1 && (fmaxf(q * m1.y, q * m1.z) - m >= THRESH);  // 256..511
    bool p3 = p2 && (fmaxf(q * m1.w, q * m2.x) - m >= THRESH);  // 512..1023
    const float4* B = blk + (size_t)node * BLK_F4;
    float4 t1[3], t2[4], t3[8];
    if (p1) {
#pragma unroll
      for (int t = 0; t < 3; ++t) t1[t] = B[64 + 64 * t + lane];
    }
    if (p2) {
#pragma unroll
      for (int t = 0; t < 4; ++t) t2[t] = B[256 + 64 * t + lane];
    }
    if (p3) {
#pragma unroll
      for (int t = 0; t < 8; ++t) t3[t] = B[512 + 64 * t + lane];
    }
    float el = __expf(q * kl - m);
    float w0 = __expf(fmaf(q, C0.x, -m));
    float w1 = __expf(fmaf(q, C0.z, -m));
    float sw = w0 + w1;
    float swv = fmaf(w0, C0.y, w1 * C0.w);
    if (p1) {
#pragma unroll
      for (int t = 0; t < 3; ++t) {
        float a0 = __expf(fmaf(q, t1[t].x, -m));
        float a1 = __expf(fmaf(q, t1[t].z, -m));
        sw += a0 + a1;
        swv = fmaf(a0, t1[t].y, fmaf(a1, t1[t].w, swv));
      }
    }
    if (p2) {
#pragma unroll
      for (int t = 0; t < 4; ++t) {
        float a0 = __expf(fmaf(q, t2[t].x, -m));
        float a1 = __expf(fmaf(q, t2[t].z, -m));
        sw += a0 + a1;
        swv = fmaf(a0, t2[t].y, fmaf(a1, t2[t].w, swv));
      }
    }
    if (p3) {
#pragma unroll
      for (int t = 0; t < 8; ++t) {
        float a0 = __expf(fmaf(q, t3[t].x, -m));
        float a1 = __expf(fmaf(q, t3[t].z, -m));
        if (t == 7 && lane == 63) a1 = 0.f;  // pair 1023 desc = median dup
        sw += a0 + a1;
        swv = fmaf(a0, t3[t].y, fmaf(a1, t3[t].w, swv));
      }
    }
    wave_sum2(sw, swv);
    float S = rl63(sw) + el;
    float SV = fmaf(el, vl, rl63(swv));
    float z = SV * __builtin_amdgcn_rcpf(S);
    float eo = __expf(2.f * z);
    float o = 1.f - 2.f * __builtin_amdgcn_rcpf(eo + 1.f);
    if (lane == 0 && node >= N_NODES - OUT_SIZE)
      souts[node - (N_NODES - OUT_SIZE)] = o;
    if (lane < cnt) {
      int n = __float_as_int(ENT.x);
      atomicAdd(&sQKV[n].x, o * ENT.y);
      atomicAdd(&sQKV[n].y, o * ENT.z);
      atomicAdd(&sQKV[n].z, o * ENT.w);
    }
  };

  // prefetch: chunk0 + entries into regs; L2-warm the tail region (static
  // addresses only — sOrder/sStart/blk — so safe to issue before the level's
  // scatters are visible).
  auto prefetch = [&](int LL, int& pn, float4& c0, float4& ent) {
    pn = -1;
    if (LL < nlev) {
      int j = sStart[LL] + w;
      if (j < sStart[LL + 1]) {
        pn = sOrder[j];
        const float4* B = blk + (size_t)pn * BLK_F4;
        c0 = B[lane];
        ent = B[1024 + lane];
        const char* tb = (const char*)(B + 64);  // tails: 15360 B = 120 lines
        warm16(tb + (size_t)lane * 128, &sTrash[0]);
        warm16(tb + 7680 + (size_t)lane * 128, &sTrash[0]);
      }
    }
  };

  int pnA, pnB;
  float4 c0A = make_float4(0.f, 0.f, 0.f, 0.f), entA = c0A;
  float4 c0B = c0A, entB = c0A;
  prefetch(0, pnA, c0A, entA);
  __syncthreads();

  int L = 0;
  while (true) {
    // ---- level L: consume set A, issue set B (level L+1) at top ----
    prefetch(L + 1, pnB, c0B, entB);
    if (pnA >= 0) process(pnA, c0A, entA);
    for (int i = sStart[L] + w + 16; i < sStart[L + 1]; i += 16) {
      int n2 = sOrder[i];
      const float4* B2 = blk + (size_t)n2 * BLK_F4;
      process(n2, B2[lane], B2[1024 + lane]);
    }
    asm volatile("s_waitcnt lgkmcnt(0)" ::: "memory");  // LDS scatters visible
    __builtin_amdgcn_s_barrier();
    asm volatile("" ::: "memory");  // no LDS reads hoisted above barrier
    ++L; if (L >= nlev) break;

    // ---- level L: consume set B, issue set A (level L+1) at top ----
    prefetch(L + 1, pnA, c0A, entA);
    if (pnB >= 0) process(pnB, c0B, entB);
    for (int i = sStart[L] + w + 16; i < sStart[L + 1]; i += 16) {
      int n2 = sOrder[i];
      const float4* B2 = blk + (size_t)n2 * BLK_F4;
      process(n2, B2[lane], B2[1024 + lane]);
    }
    asm volatile("s_waitcnt lgkmcnt(0)" ::: "memory");
    __builtin_amdgcn_s_barrier();
    asm volatile("" ::: "memory");
    ++L; if (L >= nlev) break;
  }
  // drain any outstanding warm loads before workgroup teardown
  asm volatile("s_waitcnt vmcnt(0)" ::: "memory");
  __syncthreads();
  if (tid < OUT_SIZE) out[tid] = souts[tid];
}

// ---------------------------------------------------------------------------
extern "C" void kernel_launch(void* const* d_in, const int* in_sizes, int n_in,
                              void* d_out, int out_size, void* d_ws,
                              size_t ws_size, hipStream_t stream) {
  const float* x = (const float*)d_in[0];
  const float* actives = (const float*)d_in[1];
  const float* weights = (const float*)d_in[2];
  const int* in_idxs = (const int*)d_in[3];
  float* out = (float*)d_out;

  // workspace (~9.1 MB): blk | meta_g | Qb | w12
  char* ws = (char*)d_ws;
  float4* blk = (float4*)ws;  // 512 * 1088 * 16 = 8,912,896 B
  size_t off = (size_t)N_NODES * BLK_F4 * 16;
  float4* meta_g = (float4*)(ws + off); off += (size_t)N_NODES * 3 * 16;
  float4* Qb = (float4*)(ws + off); off += (size_t)N_NODES * 16;
  float2* w12 = (float2*)(ws + off);

  prep_kernel<<<TOTAL_EDGE / 256, 256, 0, stream>>>(weights, w12);
  kv_kernel<<<(T_DIM / 8) * 2, 256, 0, stream>>>(actives, in_idxs, w12,
                                                 (float2*)blk);
  block_kernel<<<N_NODES, 256, 0, stream>>>(x, in_idxs, weights, blk, meta_g,
                                            Qb);
  sweep_kernel<<<1, 1024, 0, stream>>>(in_idxs, Qb, meta_g, blk, out);
}

// Round 3
// 175.279 us; speedup vs baseline: 1.6676x; 1.6676x over previous
//
#include <hip/hip_runtime.h>

#define IN_SIZE 256
#define OUT_SIZE 64
#define N_NODES 512
#define FAN_IN 32
#define T_DIM 2048
#define D_DIM 832
#define TOTAL_EDGE 16384
#define BLK_F4 1088   // per-node: 1024 f4 butterfly pairs + 64 f4 entries
#define MAX_ENT 64
#define THRESH -20.0f

// DPP wave64 sum (lane 63 ends with total) — validated rounds 3..9
template <int CTRL, int RM>
__device__ __forceinline__ float dppadd(float v) {
  int m = __builtin_amdgcn_update_dpp(0, __float_as_int(v), CTRL, RM, 0xf, true);
  return v + __int_as_float(m);
}
__device__ __forceinline__ void wave_sum2(float& a, float& b) {
  a = dppadd<0x111, 0xf>(a); b = dppadd<0x111, 0xf>(b);
  a = dppadd<0x112, 0xf>(a); b = dppadd<0x112, 0xf>(b);
  a = dppadd<0x114, 0xf>(a); b = dppadd<0x114, 0xf>(b);
  a = dppadd<0x118, 0xf>(a); b = dppadd<0x118, 0xf>(b);
  a = dppadd<0x142, 0xa>(a); b = dppadd<0x142, 0xa>(b);
  a = dppadd<0x143, 0xc>(a); b = dppadd<0x143, 0xc>(b);
}
__device__ __forceinline__ float rl63(float v) {
  return __int_as_float(__builtin_amdgcn_readlane(__float_as_int(v), 63));
}

// ---------------------------------------------------------------------------
// Prep: repack (w1,w2) -> coalesced float2 for kv_kernel. Pure map.
// ---------------------------------------------------------------------------
__global__ __launch_bounds__(256) void prep_kernel(
    const float* __restrict__ weights, float2* __restrict__ w12) {
  int e = blockIdx.x * 256 + threadIdx.x;
  if (e >= TOTAL_EDGE) return;
  const float* wp = weights + (size_t)e * 3;
  w12[e] = make_float2(wp[1], wp[2]);
}

// ---------------------------------------------------------------------------
// KV build (t-major, rows staged in LDS). 2 blocks per 8-row group, 4
// node-tiles each. Rows staged as float4; weights from w12 repack.
// Writes (k,v) t-order into blk KV area; slot 2047 = 0.
// ---------------------------------------------------------------------------
__global__ __launch_bounds__(256) void kv_kernel(
    const float* __restrict__ actives, const int* __restrict__ in_idxs,
    const float2* __restrict__ w12, float2* __restrict__ KVd) {
  __shared__ float rows[8][836];  // 836 floats/row: float4-aligned row base
  __shared__ int s_idx[64 * FAN_IN];
  __shared__ float2 s_w[64 * FAN_IN];
  int tid = threadIdx.x;
  int tb = (blockIdx.x >> 1) * 8;
  int t0 = (blockIdx.x & 1) * 4;
#pragma unroll
  for (int r = 0; r < 8; ++r) {
    int t = tb + r;
    for (int c = tid; c < 208; c += 256) {  // 208 float4 = 832 floats
      float4 v4 = make_float4(0.f, 0.f, 0.f, 0.f);
      if (t < T_DIM - 1)
        v4 = ((const float4*)(actives + (size_t)(t + 1) * D_DIM))[c];
      *(float4*)&rows[r][4 * c] = v4;
    }
  }
  int tl = tid & 7, ng = tid >> 3;
  for (int tile = t0; tile < t0 + 4; ++tile) {
    __syncthreads();
    int n0 = tile * 64;
    for (int i = tid; i < 64 * FAN_IN; i += 256) {
      int g = n0 * FAN_IN + i;
      s_idx[i] = in_idxs[g];
      s_w[i] = w12[g];
    }
    __syncthreads();
#pragma unroll
    for (int it = 0; it < 2; ++it) {
      int nl = ng + 32 * it;
      const int* ip = &s_idx[nl * FAN_IN];
      const float2* wp = &s_w[nl * FAN_IN];
      float k = 0.f, v = 0.f;
#pragma unroll 8
      for (int f = 0; f < FAN_IN; ++f) {
        float a = rows[tl][ip[f]];
        float2 w = wp[f];
        k = fmaf(w.x, a, k);
        v = fmaf(w.y, a, v);
      }
      KVd[(size_t)(n0 + nl) * (2 * BLK_F4) + tb + tl] = make_float2(k, v);
    }
  }
}

// ---------------------------------------------------------------------------
// Block build: bucket-sort k ascending -> butterfly pairs
// B[p]=(asc_k,asc_v,desc_k,desc_v) p<1024; entries at B[1024..1087]
// (consumers c > node ONLY — dead edges c<=node read 0 in the reference).
// meta (kmax/kmin/cnt + skip bounds at 64-pair chunk0) -> meta_g; base -> Qb.
// ---------------------------------------------------------------------------
__global__ __launch_bounds__(256) void block_kernel(
    const float* __restrict__ x, const int* __restrict__ in_idxs,
    const float* __restrict__ weights, float4* __restrict__ blk,
    float4* __restrict__ meta_g, float4* __restrict__ Qb) {
  __shared__ float2 skv[T_DIM], sbk[T_DIM];
  __shared__ int hist[64];
  __shared__ float smx[4], smn[4];
  __shared__ float4 sEnt[MAX_ENT];
  __shared__ int ecnt;
  int node = blockIdx.x, tid = threadIdx.x;
  if (tid == 0) ecnt = 0;
  const float2* src = (const float2*)(blk + (size_t)node * BLK_F4);
  float mx = -3.4e38f, mn = 3.4e38f;
#pragma unroll
  for (int j = 0; j < 8; ++j) {
    int t = j * 256 + tid;
    float2 kv = (t < 2047) ? src[t] : make_float2(0.f, 0.f);
    skv[t] = kv;
    if (t < 2047) { mx = fmaxf(mx, kv.x); mn = fminf(mn, kv.x); }
  }
  if (tid < 64) hist[tid] = 0;
#pragma unroll
  for (int off = 32; off > 0; off >>= 1) {
    mx = fmaxf(mx, __shfl_xor(mx, off));
    mn = fminf(mn, __shfl_xor(mn, off));
  }
  if ((tid & 63) == 0) { smx[tid >> 6] = mx; smn[tid >> 6] = mn; }
  __syncthreads();
  float kmax = fmaxf(fmaxf(smx[0], smx[1]), fmaxf(smx[2], smx[3]));
  float kmin = fminf(fminf(smn[0], smn[1]), fminf(smn[2], smn[3]));
  float invbw = 64.0f / (kmax - kmin);
#pragma unroll
  for (int j = 0; j < 8; ++j) {
    int t = j * 256 + tid;
    if (t < 2047) {
      int b = (int)((skv[t].x - kmin) * invbw);
      b = b < 0 ? 0 : (b > 63 ? 63 : b);
      atomicAdd(&hist[b], 1);
    }
  }
  // consumer entries: edges e with in_idxs[e]==256+node and consumer > node
  {
    int target = IN_SIZE + node;
    for (int e = tid; e < TOTAL_EDGE; e += 256) {
      if (in_idxs[e] == target) {
        int c = e >> 5;
        if (c > node) {
          int p = atomicAdd(&ecnt, 1);
          if (p < MAX_ENT) {
            const float* wp = weights + (size_t)e * 3;
            sEnt[p] = make_float4(__int_as_float(c), wp[0], wp[1], wp[2]);
          }
        }
      }
    }
  }
  __syncthreads();
  if (tid < 64) {
    int v = hist[tid];
    int incl = v;
#pragma unroll
    for (int d = 1; d < 64; d <<= 1) {
      int u = __shfl_up(incl, d);
      if (tid >= d) incl += u;
    }
    hist[tid] = incl - v;
  }
  if (tid == 0) sbk[2047] = make_float2(0.f, 0.f);
  __syncthreads();
#pragma unroll
  for (int j = 0; j < 8; ++j) {
    int t = j * 256 + tid;
    if (t < 2047) {
      int b = (int)((skv[t].x - kmin) * invbw);
      b = b < 0 ? 0 : (b > 63 ? 63 : b);
      int p = atomicAdd(&hist[b], 1);
      sbk[p] = skv[t];
    }
  }
  // base dot from x (node inputs >= IN_SIZE contribute via scatters)
  if (tid < 32) {
    int g = node * FAN_IN + tid;
    int idx = in_idxs[g];
    const float* wp = weights + (size_t)g * 3;
    float a = (idx < IN_SIZE) ? x[idx] : 0.f;
    float p0 = a * wp[0], p1 = a * wp[1], p2 = a * wp[2];
#pragma unroll
    for (int off = 16; off > 0; off >>= 1) {
      p0 += __shfl_xor(p0, off);
      p1 += __shfl_xor(p1, off);
      p2 += __shfl_xor(p2, off);
    }
    if (tid == 0) Qb[node] = make_float4(p0, p1, p2, 0.f);
  }
  __syncthreads();
  float4* B = blk + (size_t)node * BLK_F4;
  for (int i = tid; i < 1024; i += 256) {
    float2 a = sbk[i];
    float2 d = sbk[2046 - i];
    B[i] = make_float4(a.x, a.y, d.x, d.y);
  }
  int cnt = ecnt < MAX_ENT ? ecnt : MAX_ENT;
  if (tid < MAX_ENT)
    B[1024 + tid] = (tid < cnt) ? sEnt[tid] : make_float4(0.f, 0.f, 0.f, 0.f);
  if (tid == 0)
    meta_g[3 * node + 0] =
        make_float4(kmax, kmin, __int_as_float(cnt), sbk[64].x);
  if (tid == 1)
    meta_g[3 * node + 1] =
        make_float4(sbk[1982].x, sbk[256].x, sbk[1790].x, sbk[512].x);
  if (tid == 2)
    meta_g[3 * node + 2] = make_float4(sbk[1534].x, 0.f, 0.f, 0.f);
}

// ---------------------------------------------------------------------------
// DATAFLOW sweep: 1 block x 1024 thr (16 waves). No levels, no barriers in
// the main loop. Node index IS a topological order (only preds p < node are
// live). Wave w owns nodes w, w+16, ... (exactly 32 each), processed in
// order. Readiness: sRecv[n] (LDS) counts producer signals; sNeed[n] = live
// in-edge count (from in_idxs). Producers scatter qkv atomics, drain
// lgkmcnt(0), then signal. Consumers spin on sRecv — deadlock-free by
// induction on node index (capped as a guard). A/B prefetch of chunk0/
// entries/meta issued before each spin so global latency hides under waits.
// ---------------------------------------------------------------------------
__global__ __launch_bounds__(1024) void sweep_kernel(
    const int* __restrict__ in_idxs, const float4* __restrict__ Qb,
    const float4* __restrict__ meta_g, const float4* __restrict__ blk,
    float* __restrict__ out) {
  __shared__ float4 sQKV[N_NODES];
  __shared__ float4 sMeta[N_NODES][3];
  __shared__ int sRecv[N_NODES];
  __shared__ int sNeed[N_NODES];
  __shared__ float souts[OUT_SIZE];
  const int tid = threadIdx.x;
  const int lane = tid & 63;
  const int w = tid >> 6;

  for (int n = tid; n < N_NODES; n += 1024) {
    sQKV[n] = Qb[n];
    sMeta[n][0] = meta_g[3 * n + 0];
    sMeta[n][1] = meta_g[3 * n + 1];
    sMeta[n][2] = meta_g[3 * n + 2];
    sRecv[n] = 0;
  }
  // live in-edge count per node (idx >= IN_SIZE and producer < node)
  if (tid < N_NODES) {
    const int4* ip = (const int4*)(in_idxs + tid * FAN_IN);
    int need = 0;
#pragma unroll
    for (int j = 0; j < 8; ++j) {
      int4 v = ip[j];
      need += (v.x >= IN_SIZE && v.x - IN_SIZE < tid);
      need += (v.y >= IN_SIZE && v.y - IN_SIZE < tid);
      need += (v.z >= IN_SIZE && v.z - IN_SIZE < tid);
      need += (v.w >= IN_SIZE && v.w - IN_SIZE < tid);
    }
    sNeed[tid] = need;
  }
  __syncthreads();

  auto process = [&](int node, float4 C0, float4 ENT, float4 m0, float4 m1,
                     float4 m2) {
    float4 qv = sQKV[node];
    float q = qv.x, kl = qv.y, vl = qv.z;
    int cnt = __float_as_int(m0.z);
    float m = fmaxf(fmaxf(q * m0.x, q * m0.y), q * kl);
    bool p1 = fmaxf(q * m0.w, q * m1.x) - m >= THRESH;          // pairs 64..255
    bool p2 = p1 && (fmaxf(q * m1.y, q * m1.z) - m >= THRESH);  // 256..511
    bool p3 = p2 && (fmaxf(q * m1.w, q * m2.x) - m >= THRESH);  // 512..1023
    const float4* B = blk + (size_t)node * BLK_F4;
    float4 t1[3], t2[4], t3[8];
    if (p1) {
#pragma unroll
      for (int t = 0; t < 3; ++t) t1[t] = B[64 + 64 * t + lane];
    }
    if (p2) {
#pragma unroll
      for (int t = 0; t < 4; ++t) t2[t] = B[256 + 64 * t + lane];
    }
    if (p3) {
#pragma unroll
      for (int t = 0; t < 8; ++t) t3[t] = B[512 + 64 * t + lane];
    }
    float el = __expf(q * kl - m);
    float w0 = __expf(fmaf(q, C0.x, -m));
    float w1 = __expf(fmaf(q, C0.z, -m));
    float sw = w0 + w1;
    float swv = fmaf(w0, C0.y, w1 * C0.w);
    if (p1) {
#pragma unroll
      for (int t = 0; t < 3; ++t) {
        float a0 = __expf(fmaf(q, t1[t].x, -m));
        float a1 = __expf(fmaf(q, t1[t].z, -m));
        sw += a0 + a1;
        swv = fmaf(a0, t1[t].y, fmaf(a1, t1[t].w, swv));
      }
    }
    if (p2) {
#pragma unroll
      for (int t = 0; t < 4; ++t) {
        float a0 = __expf(fmaf(q, t2[t].x, -m));
        float a1 = __expf(fmaf(q, t2[t].z, -m));
        sw += a0 + a1;
        swv = fmaf(a0, t2[t].y, fmaf(a1, t2[t].w, swv));
      }
    }
    if (p3) {
#pragma unroll
      for (int t = 0; t < 8; ++t) {
        float a0 = __expf(fmaf(q, t3[t].x, -m));
        float a1 = __expf(fmaf(q, t3[t].z, -m));
        if (t == 7 && lane == 63) a1 = 0.f;  // pair 1023 desc = median dup
        sw += a0 + a1;
        swv = fmaf(a0, t3[t].y, fmaf(a1, t3[t].w, swv));
      }
    }
    wave_sum2(sw, swv);
    float S = rl63(sw) + el;
    float SV = fmaf(el, vl, rl63(swv));
    float z = SV * __builtin_amdgcn_rcpf(S);
    float eo = __expf(2.f * z);
    float o = 1.f - 2.f * __builtin_amdgcn_rcpf(eo + 1.f);
    if (lane == 0 && node >= N_NODES - OUT_SIZE)
      souts[node - (N_NODES - OUT_SIZE)] = o;
    // scatter to consumers, then release-signal (scatters drained first)
    if (lane < cnt) {
      int c = __float_as_int(ENT.x);
      atomicAdd(&sQKV[c].x, o * ENT.y);
      atomicAdd(&sQKV[c].y, o * ENT.z);
      atomicAdd(&sQKV[c].z, o * ENT.w);
    }
    asm volatile("s_waitcnt lgkmcnt(0)" ::: "memory");
    if (lane < cnt) {
      int c = __float_as_int(ENT.x);
      atomicAdd(&sRecv[c], 1);
    }
  };

  auto pf = [&](int n, float4& c0, float4& ent, float4& m0, float4& m1,
                float4& m2) {
    const float4* B = blk + (size_t)n * BLK_F4;
    c0 = B[lane];
    ent = B[1024 + lane];
    m0 = sMeta[n][0];
    m1 = sMeta[n][1];
    m2 = sMeta[n][2];
  };

  auto spinwait = [&](int n) {
    int need = sNeed[n];
    if (need > 0) {
      const volatile int* rp = (const volatile int*)&sRecv[n];
      int it = 0;
      while (*rp < need && ++it < 1000000) __builtin_amdgcn_s_sleep(1);
    }
    asm volatile("" ::: "memory");  // no sQKV read hoisted above readiness
  };

  float4 c0A, entA, m0A, m1A, m2A;
  float4 c0B, entB, m0B, m1B, m2B;
  pf(w, c0A, entA, m0A, m1A, m2A);
  for (int n = w; n < N_NODES; n += 32) {
    pf(n + 16, c0B, entB, m0B, m1B, m2B);
    spinwait(n);
    process(n, c0A, entA, m0A, m1A, m2A);
    if (n + 32 < N_NODES) pf(n + 32, c0A, entA, m0A, m1A, m2A);
    spinwait(n + 16);
    process(n + 16, c0B, entB, m0B, m1B, m2B);
  }
  __syncthreads();
  if (tid < OUT_SIZE) out[tid] = souts[tid];
}

// ---------------------------------------------------------------------------
extern "C" void kernel_launch(void* const* d_in, const int* in_sizes, int n_in,
                              void* d_out, int out_size, void* d_ws,
                              size_t ws_size, hipStream_t stream) {
  const float* x = (const float*)d_in[0];
  const float* actives = (const float*)d_in[1];
  const float* weights = (const float*)d_in[2];
  const int* in_idxs = (const int*)d_in[3];
  float* out = (float*)d_out;

  // workspace (~9.1 MB): blk | meta_g | Qb | w12
  char* ws = (char*)d_ws;
  float4* blk = (float4*)ws;  // 512 * 1088 * 16 = 8,912,896 B
  size_t off = (size_t)N_NODES * BLK_F4 * 16;
  float4* meta_g = (float4*)(ws + off); off += (size_t)N_NODES * 3 * 16;
  float4* Qb = (float4*)(ws + off); off += (size_t)N_NODES * 16;
  float2* w12 = (float2*)(ws + off);

  prep_kernel<<<TOTAL_EDGE / 256, 256, 0, stream>>>(weights, w12);
  kv_kernel<<<(T_DIM / 8) * 2, 256, 0, stream>>>(actives, in_idxs, w12,
                                                 (float2*)blk);
  block_kernel<<<N_NODES, 256, 0, stream>>>(x, in_idxs, weights, blk, meta_g,
                                            Qb);
  sweep_kernel<<<1, 1024, 0, stream>>>(in_idxs, Qb, meta_g, blk, out);
}